// Round 17
// baseline (195.689 us; speedup 1.0000x reference)
//
#include <hip/hip_runtime.h>
#include <hip/hip_bf16.h>

typedef short bf16x8 __attribute__((ext_vector_type(8)));
typedef float f32x4 __attribute__((ext_vector_type(4)));

#define E_TOTAL 2000000
#define MT 64
#define NTILES (E_TOTAL / MT)    // 31250 exactly
#define NBLK4 ((NTILES + 3) / 4) // 7813 blocks, 4 tiles each (last block: 2 valid)

#define NU 100000
#define NV 20000
#define NBU ((NU + 63) / 64)    // 1563
#define NBV ((NV + 63) / 64)    // 313

// ws layout (ushort element offsets)
#define OFF_W1UG 0              // 64x64 transposed bf16(W1u)
#define OFF_W1VG 4096           // 64x64 transposed bf16(W1v)
#define OFF_B2G  8192           // 80x64 transposed bf16([W2 | W2@Wp | 0])
#define OFF_U1   16384          // 100000x64 bf16
#define OFF_V1   (16384 + 6400000)
#define WS_NEEDED_BYTES ((size_t)(OFF_V1 + 1280000) * 2)   // 15,392,768 B

// fallback (old path) ws layout: W1g (64x128) @0, B2g @8192
#define FB_XP 136
#define FB_GP 72

__device__ __forceinline__ unsigned short f2bf(float x) {
  __hip_bfloat16 h = __float2bfloat16(x);
  return __builtin_bit_cast(unsigned short, h);
}
__device__ __forceinline__ float bf2f(unsigned short u) {
  unsigned int v = ((unsigned int)u) << 16;
  return __builtin_bit_cast(float, v);
}
__device__ __forceinline__ float gelu_exact(float x) {
  return 0.5f * x * (1.0f + erff(x * 0.70710678118654752f));
}
// Branch-free tanh-GELU (max dev from exact ~2e-4, below bf16 rounding).
__device__ __forceinline__ float gelu_fast(float x) {
  float x2 = x * x;
  float inner = __builtin_fmaf(0.044715f * x, x2, x);
  float e = __builtin_amdgcn_exp2f(inner * 2.3022081f);   // 2*k*log2(e)
  float r = __builtin_amdgcn_rcpf(e + 1.0f);
  return __builtin_fmaf(-x, r, x);
}

// ---------------- prep: weight repack ----------------
__global__ void prep_w(const float* __restrict__ W1, const float* __restrict__ W2,
                       const float* __restrict__ Wp, unsigned short* __restrict__ ws) {
  int t = blockIdx.x * blockDim.x + threadIdx.x;
  int stride = gridDim.x * blockDim.x;
  unsigned short* W1ug = ws + OFF_W1UG;
  unsigned short* W1vg = ws + OFF_W1VG;
  unsigned short* B2g  = ws + OFF_B2G;
  for (int i = t; i < 4096; i += stride) {
    int n = i >> 6, k = i & 63;
    int xc = 32 * (k >> 4) + (k & 15);
    W1ug[i] = f2bf(W1[xc * 64 + n]);
    W1vg[i] = f2bf(W1[(xc + 16) * 64 + n]);
  }
  for (int i = t; i < 80 * 64; i += stride) {
    int n = i >> 6, k = i & 63;
    float v;
    if (n < 64) {
      v = W2[k * 64 + n];
    } else if (n < 69) {
      int c = n - 64;
      float s = 0.f;
      for (int j = 0; j < 64; ++j) s += W2[k * 64 + j] * Wp[j * 5 + c];
      v = s;
    } else {
      v = 0.f;
    }
    B2g[i] = f2bf(v);
  }
}

// ---------------- prep: U1 = ufeat@W1u, V1 = ifeat@W1v (bf16 out, swapped MFMA) ----------------
__global__ __launch_bounds__(256)
void prep_uv(const float* __restrict__ ufeat, const float* __restrict__ ifeat,
             const unsigned short* __restrict__ ws, unsigned short* __restrict__ wsmut) {
  const bool isU = (blockIdx.x < NBU);
  const int rows0 = (isU ? blockIdx.x : blockIdx.x - NBU) * 64;
  const int nrows = isU ? NU : NV;
  const float* feat = isU ? ufeat : ifeat;
  const unsigned short* Wg = ws + (isU ? OFF_W1UG : OFF_W1VG);
  unsigned short* outp = wsmut + (isU ? OFF_U1 : OFF_V1);

  const int lane = threadIdx.x & 63;
  const int w    = threadIdx.x >> 6;
  const int lr   = lane & 15;
  const int q    = lane >> 4;

  int row = rows0 + w * 16 + lr;
  int rowc = row < nrows ? row : nrows - 1;

  const f32x4 fz = {0.f, 0.f, 0.f, 0.f};
  f32x4 acc[4] = {fz, fz, fz, fz};
  #pragma unroll
  for (int kk = 0; kk < 2; ++kk) {
    int k0 = kk * 32 + q * 8;
    float4 fa = *reinterpret_cast<const float4*>(feat + (size_t)rowc * 64 + k0);
    float4 fb = *reinterpret_cast<const float4*>(feat + (size_t)rowc * 64 + k0 + 4);
    bf16x8 a;
    a[0] = (short)f2bf(fa.x); a[1] = (short)f2bf(fa.y);
    a[2] = (short)f2bf(fa.z); a[3] = (short)f2bf(fa.w);
    a[4] = (short)f2bf(fb.x); a[5] = (short)f2bf(fb.y);
    a[6] = (short)f2bf(fb.z); a[7] = (short)f2bf(fb.w);
    #pragma unroll
    for (int nt = 0; nt < 4; ++nt) {
      bf16x8 b = *reinterpret_cast<const bf16x8*>(&Wg[(nt * 16 + lr) * 64 + k0]);
      acc[nt] = __builtin_amdgcn_mfma_f32_16x16x32_bf16(b, a, acc[nt], 0, 0, 0);
    }
  }
  // swapped C layout: acc[nt][r] = out[row][nt*16+4q+r]
  if (row < nrows) {
    #pragma unroll
    for (int nt = 0; nt < 4; ++nt) {
      ushort4 p;
      p.x = f2bf(acc[nt][0]); p.y = f2bf(acc[nt][1]);
      p.z = f2bf(acc[nt][2]); p.w = f2bf(acc[nt][3]);
      *reinterpret_cast<ushort4*>(&outp[(size_t)row * 64 + nt * 16 + 4 * q]) = p;
    }
  }
}

// ---------------- per-tile compute: GELU(u+v) -> swapped GEMM2 -> coalesced NT store ----------------
// mfma(B2_frag, g_frag, acc): lane (lr,q) reg r = h[edge=tbase+w*16+lr][col=nt*16+4q+r]
__device__ __forceinline__ void tile_compute(
    const unsigned short* __restrict__ B2g,
    bf16x8 u0, bf16x8 u1, bf16x8 v0, bf16x8 v1,
    int tbase, bool valid, int w, int lr, int q, float* __restrict__ out) {
  const f32x4 fz = {0.f, 0.f, 0.f, 0.f};
  f32x4 acc[5] = {fz, fz, fz, fz, fz};
  bf16x8 g0, g1;
  #pragma unroll
  for (int e = 0; e < 8; ++e) {
    float x = bf2f((unsigned short)u0[e]) + bf2f((unsigned short)v0[e]);
    g0[e] = (short)f2bf(gelu_fast(x));
  }
  #pragma unroll
  for (int e = 0; e < 8; ++e) {
    float y = bf2f((unsigned short)u1[e]) + bf2f((unsigned short)v1[e]);
    g1[e] = (short)f2bf(gelu_fast(y));
  }
  const int k0 = q * 8;
  #pragma unroll
  for (int nt = 0; nt < 5; ++nt) {
    // same addresses for every tile -> compiler CSEs/rematerializes as regalloc allows
    bf16x8 b0 = *reinterpret_cast<const bf16x8*>(&B2g[(nt * 16 + lr) * 64 + k0]);
    bf16x8 b1 = *reinterpret_cast<const bf16x8*>(&B2g[(nt * 16 + lr) * 64 + 32 + k0]);
    acc[nt] = __builtin_amdgcn_mfma_f32_16x16x32_bf16(b0, g0, acc[nt], 0, 0, 0);
    acc[nt] = __builtin_amdgcn_mfma_f32_16x16x32_bf16(b1, g1, acc[nt], 0, 0, 0);
  }
  if (!valid) return;
  float* out_score = out;                 // [E,5]
  float* out_h     = out + 10000000;      // [E,64]
  const size_t edge = (size_t)(tbase + w * 16 + lr);
  #pragma unroll
  for (int nt = 0; nt < 4; ++nt)
    __builtin_nontemporal_store(acc[nt],
        reinterpret_cast<f32x4*>(&out_h[edge * 64 + nt * 16 + 4 * q]));
  if (q == 0) {
    *reinterpret_cast<f32x4*>(&out_score[edge * 5]) = acc[4];   // cols 0..3
  } else if (q == 1) {
    out_score[edge * 5 + 4] = acc[4][0];                        // col 68 -> score col 4
  }
}

// ---------------- main: 4-tile pipelined, barrier-free, no LDS ----------------
// All 8 idx loads + 16 gathers issued before tile A's compute; counted vmcnt
// leaves later tiles' loads in flight while earlier tiles compute.
__global__ __launch_bounds__(256, 5)
void mlp_main11(const unsigned short* __restrict__ ws,
                const int* __restrict__ src, const int* __restrict__ dst,
                float* __restrict__ out) {
  const unsigned short* U1  = ws + OFF_U1;
  const unsigned short* V1  = ws + OFF_V1;
  const unsigned short* B2g = ws + OFF_B2G;

  const int lane = threadIdx.x & 63;
  const int w    = threadIdx.x >> 6;
  const int lr   = lane & 15;
  const int q    = lane >> 4;
  const int q8   = q * 8;
  const int elane = w * 16 + lr;

  const int t0 = blockIdx.x * 4;
  const int t1 = t0 + 1;
  const int t2 = t0 + 2;
  const int t3 = t0 + 3;
  const bool v2 = (t2 < NTILES);          // only the last block's tiles C/D can overflow
  const bool v3 = (t3 < NTILES);
  const int tc2 = v2 ? t2 : 0;            // clamp loads to a valid tile
  const int tc3 = v3 ? t3 : 0;

  const int eA = t0 * MT + elane;
  const int eB = t1 * MT + elane;
  const int eC = tc2 * MT + elane;
  const int eD = tc3 * MT + elane;

  // 8 independent idx loads
  const int iA0 = src[eA];
  const int iA1 = dst[eA];
  const int iB0 = src[eB];
  const int iB1 = dst[eB];
  const int iC0 = src[eC];
  const int iC1 = dst[eC];
  const int iD0 = src[eD];
  const int iD1 = dst[eD];

  // 16 gather loads — all issued before any compute
  const unsigned short* upA = U1 + (size_t)iA0 * 64 + q8;
  const unsigned short* vpA = V1 + (size_t)iA1 * 64 + q8;
  const unsigned short* upB = U1 + (size_t)iB0 * 64 + q8;
  const unsigned short* vpB = V1 + (size_t)iB1 * 64 + q8;
  const unsigned short* upC = U1 + (size_t)iC0 * 64 + q8;
  const unsigned short* vpC = V1 + (size_t)iC1 * 64 + q8;
  const unsigned short* upD = U1 + (size_t)iD0 * 64 + q8;
  const unsigned short* vpD = V1 + (size_t)iD1 * 64 + q8;

  bf16x8 uA0 = *reinterpret_cast<const bf16x8*>(upA);
  bf16x8 uA1 = *reinterpret_cast<const bf16x8*>(upA + 32);
  bf16x8 vA0 = *reinterpret_cast<const bf16x8*>(vpA);
  bf16x8 vA1 = *reinterpret_cast<const bf16x8*>(vpA + 32);
  bf16x8 uB0 = *reinterpret_cast<const bf16x8*>(upB);
  bf16x8 uB1 = *reinterpret_cast<const bf16x8*>(upB + 32);
  bf16x8 vB0 = *reinterpret_cast<const bf16x8*>(vpB);
  bf16x8 vB1 = *reinterpret_cast<const bf16x8*>(vpB + 32);
  bf16x8 uC0 = *reinterpret_cast<const bf16x8*>(upC);
  bf16x8 uC1 = *reinterpret_cast<const bf16x8*>(upC + 32);
  bf16x8 vC0 = *reinterpret_cast<const bf16x8*>(vpC);
  bf16x8 vC1 = *reinterpret_cast<const bf16x8*>(vpC + 32);
  bf16x8 uD0 = *reinterpret_cast<const bf16x8*>(upD);
  bf16x8 uD1 = *reinterpret_cast<const bf16x8*>(upD + 32);
  bf16x8 vD0 = *reinterpret_cast<const bf16x8*>(vpD);
  bf16x8 vD1 = *reinterpret_cast<const bf16x8*>(vpD + 32);

  tile_compute(B2g, uA0, uA1, vA0, vA1, t0 * MT, true, w, lr, q, out);
  tile_compute(B2g, uB0, uB1, vB0, vB1, t1 * MT, true, w, lr, q, out);
  tile_compute(B2g, uC0, uC1, vC0, vC1, t2 * MT, v2,   w, lr, q, out);
  tile_compute(B2g, uD0, uD1, vD0, vD1, t3 * MT, v3,   w, lr, q, out);
}

// ================= fallback path (R5 structure) if ws too small =================
__global__ void prep_kernel_fb(const float* __restrict__ W1, const float* __restrict__ W2,
                               const float* __restrict__ Wp,
                               unsigned short* __restrict__ W1g,
                               unsigned short* __restrict__ B2g) {
  int t = blockIdx.x * blockDim.x + threadIdx.x;
  int stride = gridDim.x * blockDim.x;
  for (int i = t; i < 64 * 128; i += stride) {
    int n = i >> 7, k = i & 127;
    W1g[i] = f2bf(W1[k * 64 + n]);
  }
  for (int i = t; i < 80 * 64; i += stride) {
    int n = i >> 6, k = i & 63;
    float v;
    if (n < 64) v = W2[k * 64 + n];
    else if (n < 69) {
      int c = n - 64; float s = 0.f;
      for (int j = 0; j < 64; ++j) s += W2[k * 64 + j] * Wp[j * 5 + c];
      v = s;
    } else v = 0.f;
    B2g[i] = f2bf(v);
  }
}

__global__ __launch_bounds__(256, 8)
void mlp_main_fb(const float* __restrict__ ufeat, const float* __restrict__ ifeat,
                 const int* __restrict__ src, const int* __restrict__ dst,
                 const unsigned short* __restrict__ W1g, const unsigned short* __restrict__ B2g,
                 float* __restrict__ out) {
  __shared__ __align__(16) unsigned short Xb[MT * FB_XP];
  const int lid  = threadIdx.x;
  const int lane = lid & 63;
  const int w    = lid >> 6;
  const int lr   = lane & 15;
  const int q    = lane >> 4;
  const int lk   = q << 3;
  const int tbase = blockIdx.x * MT;
  const int c  = lid & 15;
  const int rb = lid >> 4;
  int eidx[8];
  #pragma unroll
  for (int j = 0; j < 8; ++j) {
    int r = rb + 16 * j;
    eidx[j] = (r < 64) ? src[tbase + r] : dst[tbase + r - 64];
  }
  #pragma unroll
  for (int j = 0; j < 8; ++j) {
    int r = rb + 16 * j;
    int half = r >> 6;
    int e = r & 63;
    const float* base = (half ? ifeat : ufeat) + (size_t)eidx[j] * 64 + c * 4;
    float4 f = *reinterpret_cast<const float4*>(base);
    int col = ((c >> 2) * 32) + half * 16 + ((c & 3) * 4);
    ushort4 p;
    p.x = f2bf(f.x); p.y = f2bf(f.y); p.z = f2bf(f.z); p.w = f2bf(f.w);
    *reinterpret_cast<ushort4*>(&Xb[e * FB_XP + col]) = p;
  }
  __syncthreads();
  const f32x4 fz = {0.f, 0.f, 0.f, 0.f};
  f32x4 acc1[4] = {fz, fz, fz, fz};
  {
    const unsigned short* Xr = &Xb[(w * 16 + lr) * FB_XP];
    #pragma unroll
    for (int kk = 0; kk < 4; ++kk) {
      int ko = kk * 32 + lk;
      bf16x8 a = *reinterpret_cast<const bf16x8*>(Xr + ko);
      #pragma unroll
      for (int nt = 0; nt < 4; ++nt) {
        bf16x8 b = *reinterpret_cast<const bf16x8*>(&W1g[(nt * 16 + lr) * 128 + ko]);
        acc1[nt] = __builtin_amdgcn_mfma_f32_16x16x32_bf16(a, b, acc1[nt], 0, 0, 0);
      }
    }
  }
  __syncthreads();
  unsigned short* g = Xb;
  #pragma unroll
  for (int nt = 0; nt < 4; ++nt) {
    f32x4 v = acc1[nt];
    #pragma unroll
    for (int r = 0; r < 4; ++r)
      g[(w * 16 + 4 * q + r) * FB_GP + nt * 16 + lr] = f2bf(gelu_exact(v[r]));
  }
  __syncthreads();
  f32x4 acc2[5] = {fz, fz, fz, fz, fz};
  #pragma unroll
  for (int kk = 0; kk < 2; ++kk) {
    int ko = kk * 32 + lk;
    bf16x8 a = *reinterpret_cast<const bf16x8*>(&g[(w * 16 + lr) * FB_GP + ko]);
    #pragma unroll
    for (int nt = 0; nt < 5; ++nt) {
      bf16x8 b = *reinterpret_cast<const bf16x8*>(&B2g[(nt * 16 + lr) * 64 + ko]);
      acc2[nt] = __builtin_amdgcn_mfma_f32_16x16x32_bf16(a, b, acc2[nt], 0, 0, 0);
    }
  }
  float* out_score = out;
  float* out_h     = out + 10000000;
  {
    int er0 = tbase + w * 16 + 4 * q;
    #pragma unroll
    for (int nt = 0; nt < 4; ++nt) {
      #pragma unroll
      for (int r = 0; r < 4; ++r)
        out_h[(size_t)(er0 + r) * 64 + nt * 16 + lr] = acc2[nt][r];
    }
    if (lr < 5) {
      #pragma unroll
      for (int r = 0; r < 4; ++r)
        out_score[(size_t)(er0 + r) * 5 + lr] = acc2[4][r];
    }
  }
}

extern "C" void kernel_launch(void* const* d_in, const int* in_sizes, int n_in,
                              void* d_out, int out_size, void* d_ws, size_t ws_size,
                              hipStream_t stream) {
  const float* ufeat = (const float*)d_in[0];
  const float* ifeat = (const float*)d_in[1];
  const float* W1    = (const float*)d_in[2];
  const float* W2    = (const float*)d_in[3];
  const float* Wp    = (const float*)d_in[4];
  const int*   src   = (const int*)d_in[5];
  const int*   dst   = (const int*)d_in[6];

  unsigned short* ws = (unsigned short*)d_ws;

  if (ws_size >= WS_NEEDED_BYTES) {
    prep_w<<<16, 256, 0, stream>>>(W1, W2, Wp, ws);
    prep_uv<<<NBU + NBV, 256, 0, stream>>>(ufeat, ifeat, ws, ws);
    mlp_main11<<<NBLK4, 256, 0, stream>>>(ws, src, dst, (float*)d_out);
  } else {
    unsigned short* W1g = ws;
    unsigned short* B2g = ws + 8192;
    prep_kernel_fb<<<16, 256, 0, stream>>>(W1, W2, Wp, W1g, B2g);
    mlp_main_fb<<<NTILES, 256, 0, stream>>>(ufeat, ifeat, src, dst, W1g, B2g, (float*)d_out);
  }
}

// Round 18
// 180.073 us; speedup vs baseline: 1.0867x; 1.0867x over previous
//
#include <hip/hip_runtime.h>
#include <hip/hip_bf16.h>

typedef short bf16x8 __attribute__((ext_vector_type(8)));
typedef float f32x4 __attribute__((ext_vector_type(4)));

#define E_TOTAL 2000000
#define MT 64
#define NTILES (E_TOTAL / MT)   // 31250 exactly
#define NBLK3 ((NTILES + 2) / 3) // 10417 blocks, 3 tiles each (last block: 2 valid)

#define NU 100000
#define NV 20000
#define NBU ((NU + 63) / 64)    // 1563
#define NBV ((NV + 63) / 64)    // 313

// ws layout (ushort element offsets)
#define OFF_W1UG 0              // 64x64 transposed bf16(W1u)
#define OFF_W1VG 4096           // 64x64 transposed bf16(W1v)
#define OFF_B2G  8192           // 80x64 transposed bf16([W2 | W2@Wp | 0])
#define OFF_U1   16384          // 100000x64 bf16
#define OFF_V1   (16384 + 6400000)
#define WS_NEEDED_BYTES ((size_t)(OFF_V1 + 1280000) * 2)   // 15,392,768 B

// fallback (old path) ws layout: W1g (64x128) @0, B2g @8192
#define FB_XP 136
#define FB_GP 72

__device__ __forceinline__ unsigned short f2bf(float x) {
  __hip_bfloat16 h = __float2bfloat16(x);
  return __builtin_bit_cast(unsigned short, h);
}
__device__ __forceinline__ float bf2f(unsigned short u) {
  unsigned int v = ((unsigned int)u) << 16;
  return __builtin_bit_cast(float, v);
}
__device__ __forceinline__ float gelu_exact(float x) {
  return 0.5f * x * (1.0f + erff(x * 0.70710678118654752f));
}
// Branch-free tanh-GELU (max dev from exact ~2e-4, below bf16 rounding).
__device__ __forceinline__ float gelu_fast(float x) {
  float x2 = x * x;
  float inner = __builtin_fmaf(0.044715f * x, x2, x);
  float e = __builtin_amdgcn_exp2f(inner * 2.3022081f);   // 2*k*log2(e)
  float r = __builtin_amdgcn_rcpf(e + 1.0f);
  return __builtin_fmaf(-x, r, x);
}

// ---------------- prep: weight repack ----------------
__global__ void prep_w(const float* __restrict__ W1, const float* __restrict__ W2,
                       const float* __restrict__ Wp, unsigned short* __restrict__ ws) {
  int t = blockIdx.x * blockDim.x + threadIdx.x;
  int stride = gridDim.x * blockDim.x;
  unsigned short* W1ug = ws + OFF_W1UG;
  unsigned short* W1vg = ws + OFF_W1VG;
  unsigned short* B2g  = ws + OFF_B2G;
  for (int i = t; i < 4096; i += stride) {
    int n = i >> 6, k = i & 63;
    int xc = 32 * (k >> 4) + (k & 15);
    W1ug[i] = f2bf(W1[xc * 64 + n]);
    W1vg[i] = f2bf(W1[(xc + 16) * 64 + n]);
  }
  for (int i = t; i < 80 * 64; i += stride) {
    int n = i >> 6, k = i & 63;
    float v;
    if (n < 64) {
      v = W2[k * 64 + n];
    } else if (n < 69) {
      int c = n - 64;
      float s = 0.f;
      for (int j = 0; j < 64; ++j) s += W2[k * 64 + j] * Wp[j * 5 + c];
      v = s;
    } else {
      v = 0.f;
    }
    B2g[i] = f2bf(v);
  }
}

// ---------------- prep: U1 = ufeat@W1u, V1 = ifeat@W1v (bf16 out, swapped MFMA) ----------------
__global__ __launch_bounds__(256)
void prep_uv(const float* __restrict__ ufeat, const float* __restrict__ ifeat,
             const unsigned short* __restrict__ ws, unsigned short* __restrict__ wsmut) {
  const bool isU = (blockIdx.x < NBU);
  const int rows0 = (isU ? blockIdx.x : blockIdx.x - NBU) * 64;
  const int nrows = isU ? NU : NV;
  const float* feat = isU ? ufeat : ifeat;
  const unsigned short* Wg = ws + (isU ? OFF_W1UG : OFF_W1VG);
  unsigned short* outp = wsmut + (isU ? OFF_U1 : OFF_V1);

  const int lane = threadIdx.x & 63;
  const int w    = threadIdx.x >> 6;
  const int lr   = lane & 15;
  const int q    = lane >> 4;

  int row = rows0 + w * 16 + lr;
  int rowc = row < nrows ? row : nrows - 1;

  const f32x4 fz = {0.f, 0.f, 0.f, 0.f};
  f32x4 acc[4] = {fz, fz, fz, fz};
  #pragma unroll
  for (int kk = 0; kk < 2; ++kk) {
    int k0 = kk * 32 + q * 8;
    float4 fa = *reinterpret_cast<const float4*>(feat + (size_t)rowc * 64 + k0);
    float4 fb = *reinterpret_cast<const float4*>(feat + (size_t)rowc * 64 + k0 + 4);
    bf16x8 a;
    a[0] = (short)f2bf(fa.x); a[1] = (short)f2bf(fa.y);
    a[2] = (short)f2bf(fa.z); a[3] = (short)f2bf(fa.w);
    a[4] = (short)f2bf(fb.x); a[5] = (short)f2bf(fb.y);
    a[6] = (short)f2bf(fb.z); a[7] = (short)f2bf(fb.w);
    #pragma unroll
    for (int nt = 0; nt < 4; ++nt) {
      bf16x8 b = *reinterpret_cast<const bf16x8*>(&Wg[(nt * 16 + lr) * 64 + k0]);
      acc[nt] = __builtin_amdgcn_mfma_f32_16x16x32_bf16(b, a, acc[nt], 0, 0, 0);
    }
  }
  // swapped C layout: acc[nt][r] = out[row][nt*16+4q+r]
  if (row < nrows) {
    #pragma unroll
    for (int nt = 0; nt < 4; ++nt) {
      ushort4 p;
      p.x = f2bf(acc[nt][0]); p.y = f2bf(acc[nt][1]);
      p.z = f2bf(acc[nt][2]); p.w = f2bf(acc[nt][3]);
      *reinterpret_cast<ushort4*>(&outp[(size_t)row * 64 + nt * 16 + 4 * q]) = p;
    }
  }
}

// ---------------- per-tile compute: GELU(u+v) -> swapped GEMM2 -> coalesced NT store ----------------
// mfma(B2_frag, g_frag, acc): lane (lr,q) reg r = h[edge=tbase+w*16+lr][col=nt*16+4q+r]
__device__ __forceinline__ void tile_compute(
    const unsigned short* __restrict__ B2g,
    bf16x8 u0, bf16x8 u1, bf16x8 v0, bf16x8 v1,
    int tbase, bool valid, int w, int lr, int q, float* __restrict__ out) {
  const f32x4 fz = {0.f, 0.f, 0.f, 0.f};
  f32x4 acc[5] = {fz, fz, fz, fz, fz};
  bf16x8 g0, g1;
  #pragma unroll
  for (int e = 0; e < 8; ++e) {
    float x = bf2f((unsigned short)u0[e]) + bf2f((unsigned short)v0[e]);
    g0[e] = (short)f2bf(gelu_fast(x));
  }
  #pragma unroll
  for (int e = 0; e < 8; ++e) {
    float y = bf2f((unsigned short)u1[e]) + bf2f((unsigned short)v1[e]);
    g1[e] = (short)f2bf(gelu_fast(y));
  }
  const int k0 = q * 8;
  #pragma unroll
  for (int nt = 0; nt < 5; ++nt) {
    // same addresses for every tile -> compiler CSEs/rematerializes as regalloc allows
    bf16x8 b0 = *reinterpret_cast<const bf16x8*>(&B2g[(nt * 16 + lr) * 64 + k0]);
    bf16x8 b1 = *reinterpret_cast<const bf16x8*>(&B2g[(nt * 16 + lr) * 64 + 32 + k0]);
    acc[nt] = __builtin_amdgcn_mfma_f32_16x16x32_bf16(b0, g0, acc[nt], 0, 0, 0);
    acc[nt] = __builtin_amdgcn_mfma_f32_16x16x32_bf16(b1, g1, acc[nt], 0, 0, 0);
  }
  if (!valid) return;
  float* out_score = out;                 // [E,5]
  float* out_h     = out + 10000000;      // [E,64]
  const size_t edge = (size_t)(tbase + w * 16 + lr);
  #pragma unroll
  for (int nt = 0; nt < 4; ++nt)
    __builtin_nontemporal_store(acc[nt],
        reinterpret_cast<f32x4*>(&out_h[edge * 64 + nt * 16 + 4 * q]));
  if (q == 0) {
    *reinterpret_cast<f32x4*>(&out_score[edge * 5]) = acc[4];   // cols 0..3
  } else if (q == 1) {
    out_score[edge * 5 + 4] = acc[4][0];                        // col 68 -> score col 4
  }
}

// ---------------- main: 3-tile pipelined, barrier-free, no LDS ----------------
// All 6 idx loads + 12 gathers issued before tile A's compute; counted vmcnt
// leaves later tiles' loads in flight while earlier tiles compute.
// Depth sweep measured: 1->251us, 2->191us, 3->180us, 4->196us (VGPR spill).
__global__ __launch_bounds__(256, 5)
void mlp_main10(const unsigned short* __restrict__ ws,
                const int* __restrict__ src, const int* __restrict__ dst,
                float* __restrict__ out) {
  const unsigned short* U1  = ws + OFF_U1;
  const unsigned short* V1  = ws + OFF_V1;
  const unsigned short* B2g = ws + OFF_B2G;

  const int lane = threadIdx.x & 63;
  const int w    = threadIdx.x >> 6;
  const int lr   = lane & 15;
  const int q    = lane >> 4;
  const int q8   = q * 8;
  const int elane = w * 16 + lr;

  const int t0 = blockIdx.x * 3;
  const int t1 = t0 + 1;
  const int t2 = t0 + 2;
  const bool v2 = (t2 < NTILES);          // only the last block's 3rd tile can overflow
  const int tc2 = v2 ? t2 : 0;            // clamp loads to a valid tile

  const int eA = t0 * MT + elane;
  const int eB = t1 * MT + elane;
  const int eC = tc2 * MT + elane;

  // 6 independent idx loads
  const int iA0 = src[eA];
  const int iA1 = dst[eA];
  const int iB0 = src[eB];
  const int iB1 = dst[eB];
  const int iC0 = src[eC];
  const int iC1 = dst[eC];

  // 12 gather loads — all issued before any compute
  const unsigned short* upA = U1 + (size_t)iA0 * 64 + q8;
  const unsigned short* vpA = V1 + (size_t)iA1 * 64 + q8;
  const unsigned short* upB = U1 + (size_t)iB0 * 64 + q8;
  const unsigned short* vpB = V1 + (size_t)iB1 * 64 + q8;
  const unsigned short* upC = U1 + (size_t)iC0 * 64 + q8;
  const unsigned short* vpC = V1 + (size_t)iC1 * 64 + q8;

  bf16x8 uA0 = *reinterpret_cast<const bf16x8*>(upA);
  bf16x8 uA1 = *reinterpret_cast<const bf16x8*>(upA + 32);
  bf16x8 vA0 = *reinterpret_cast<const bf16x8*>(vpA);
  bf16x8 vA1 = *reinterpret_cast<const bf16x8*>(vpA + 32);
  bf16x8 uB0 = *reinterpret_cast<const bf16x8*>(upB);
  bf16x8 uB1 = *reinterpret_cast<const bf16x8*>(upB + 32);
  bf16x8 vB0 = *reinterpret_cast<const bf16x8*>(vpB);
  bf16x8 vB1 = *reinterpret_cast<const bf16x8*>(vpB + 32);
  bf16x8 uC0 = *reinterpret_cast<const bf16x8*>(upC);
  bf16x8 uC1 = *reinterpret_cast<const bf16x8*>(upC + 32);
  bf16x8 vC0 = *reinterpret_cast<const bf16x8*>(vpC);
  bf16x8 vC1 = *reinterpret_cast<const bf16x8*>(vpC + 32);

  tile_compute(B2g, uA0, uA1, vA0, vA1, t0 * MT, true, w, lr, q, out);
  tile_compute(B2g, uB0, uB1, vB0, vB1, t1 * MT, true, w, lr, q, out);
  tile_compute(B2g, uC0, uC1, vC0, vC1, t2 * MT, v2,   w, lr, q, out);
}

// ================= fallback path (R5 structure) if ws too small =================
__global__ void prep_kernel_fb(const float* __restrict__ W1, const float* __restrict__ W2,
                               const float* __restrict__ Wp,
                               unsigned short* __restrict__ W1g,
                               unsigned short* __restrict__ B2g) {
  int t = blockIdx.x * blockDim.x + threadIdx.x;
  int stride = gridDim.x * blockDim.x;
  for (int i = t; i < 64 * 128; i += stride) {
    int n = i >> 7, k = i & 127;
    W1g[i] = f2bf(W1[k * 64 + n]);
  }
  for (int i = t; i < 80 * 64; i += stride) {
    int n = i >> 6, k = i & 63;
    float v;
    if (n < 64) v = W2[k * 64 + n];
    else if (n < 69) {
      int c = n - 64; float s = 0.f;
      for (int j = 0; j < 64; ++j) s += W2[k * 64 + j] * Wp[j * 5 + c];
      v = s;
    } else v = 0.f;
    B2g[i] = f2bf(v);
  }
}

__global__ __launch_bounds__(256, 8)
void mlp_main_fb(const float* __restrict__ ufeat, const float* __restrict__ ifeat,
                 const int* __restrict__ src, const int* __restrict__ dst,
                 const unsigned short* __restrict__ W1g, const unsigned short* __restrict__ B2g,
                 float* __restrict__ out) {
  __shared__ __align__(16) unsigned short Xb[MT * FB_XP];
  const int lid  = threadIdx.x;
  const int lane = lid & 63;
  const int w    = lid >> 6;
  const int lr   = lane & 15;
  const int q    = lane >> 4;
  const int lk   = q << 3;
  const int tbase = blockIdx.x * MT;
  const int c  = lid & 15;
  const int rb = lid >> 4;
  int eidx[8];
  #pragma unroll
  for (int j = 0; j < 8; ++j) {
    int r = rb + 16 * j;
    eidx[j] = (r < 64) ? src[tbase + r] : dst[tbase + r - 64];
  }
  #pragma unroll
  for (int j = 0; j < 8; ++j) {
    int r = rb + 16 * j;
    int half = r >> 6;
    int e = r & 63;
    const float* base = (half ? ifeat : ufeat) + (size_t)eidx[j] * 64 + c * 4;
    float4 f = *reinterpret_cast<const float4*>(base);
    int col = ((c >> 2) * 32) + half * 16 + ((c & 3) * 4);
    ushort4 p;
    p.x = f2bf(f.x); p.y = f2bf(f.y); p.z = f2bf(f.z); p.w = f2bf(f.w);
    *reinterpret_cast<ushort4*>(&Xb[e * FB_XP + col]) = p;
  }
  __syncthreads();
  const f32x4 fz = {0.f, 0.f, 0.f, 0.f};
  f32x4 acc1[4] = {fz, fz, fz, fz};
  {
    const unsigned short* Xr = &Xb[(w * 16 + lr) * FB_XP];
    #pragma unroll
    for (int kk = 0; kk < 4; ++kk) {
      int ko = kk * 32 + lk;
      bf16x8 a = *reinterpret_cast<const bf16x8*>(Xr + ko);
      #pragma unroll
      for (int nt = 0; nt < 4; ++nt) {
        bf16x8 b = *reinterpret_cast<const bf16x8*>(&W1g[(nt * 16 + lr) * 128 + ko]);
        acc1[nt] = __builtin_amdgcn_mfma_f32_16x16x32_bf16(a, b, acc1[nt], 0, 0, 0);
      }
    }
  }
  __syncthreads();
  unsigned short* g = Xb;
  #pragma unroll
  for (int nt = 0; nt < 4; ++nt) {
    f32x4 v = acc1[nt];
    #pragma unroll
    for (int r = 0; r < 4; ++r)
      g[(w * 16 + 4 * q + r) * FB_GP + nt * 16 + lr] = f2bf(gelu_exact(v[r]));
  }
  __syncthreads();
  f32x4 acc2[5] = {fz, fz, fz, fz, fz};
  #pragma unroll
  for (int kk = 0; kk < 2; ++kk) {
    int ko = kk * 32 + lk;
    bf16x8 a = *reinterpret_cast<const bf16x8*>(&g[(w * 16 + lr) * FB_GP + ko]);
    #pragma unroll
    for (int nt = 0; nt < 5; ++nt) {
      bf16x8 b = *reinterpret_cast<const bf16x8*>(&B2g[(nt * 16 + lr) * 64 + ko]);
      acc2[nt] = __builtin_amdgcn_mfma_f32_16x16x32_bf16(a, b, acc2[nt], 0, 0, 0);
    }
  }
  float* out_score = out;
  float* out_h     = out + 10000000;
  {
    int er0 = tbase + w * 16 + 4 * q;
    #pragma unroll
    for (int nt = 0; nt < 4; ++nt) {
      #pragma unroll
      for (int r = 0; r < 4; ++r)
        out_h[(size_t)(er0 + r) * 64 + nt * 16 + lr] = acc2[nt][r];
    }
    if (lr < 5) {
      #pragma unroll
      for (int r = 0; r < 4; ++r)
        out_score[(size_t)(er0 + r) * 5 + lr] = acc2[4][r];
    }
  }
}

extern "C" void kernel_launch(void* const* d_in, const int* in_sizes, int n_in,
                              void* d_out, int out_size, void* d_ws, size_t ws_size,
                              hipStream_t stream) {
  const float* ufeat = (const float*)d_in[0];
  const float* ifeat = (const float*)d_in[1];
  const float* W1    = (const float*)d_in[2];
  const float* W2    = (const float*)d_in[3];
  const float* Wp    = (const float*)d_in[4];
  const int*   src   = (const int*)d_in[5];
  const int*   dst   = (const int*)d_in[6];

  unsigned short* ws = (unsigned short*)d_ws;

  if (ws_size >= WS_NEEDED_BYTES) {
    prep_w<<<16, 256, 0, stream>>>(W1, W2, Wp, ws);
    prep_uv<<<NBU + NBV, 256, 0, stream>>>(ufeat, ifeat, ws, ws);
    mlp_main10<<<NBLK3, 256, 0, stream>>>(ws, src, dst, (float*)d_out);
  } else {
    unsigned short* W1g = ws;
    unsigned short* B2g = ws + 8192;
    prep_kernel_fb<<<16, 256, 0, stream>>>(W1, W2, Wp, W1g, B2g);
    mlp_main_fb<<<NTILES, 256, 0, stream>>>(ufeat, ifeat, src, dst, W1g, B2g, (float*)d_out);
  }
}